// Round 2
// baseline (182.346 us; speedup 1.0000x reference)
//
#include <hip/hip_runtime.h>

typedef unsigned int u32;
typedef __fp16 h2 __attribute__((ext_vector_type(2)));

#define BB 8
#define KK 32
#define SS 4096
#define HH 2048
#define DD 1024
#define SP 2048   // SS/2
#define HP 1024   // HH/2
#define NSC 8     // s-chunk split in pooling
#define SPC 256   // SP/NSC

// ws layout (bytes); total 24 MiB
#define OFF_W2   0ull          // u32 half2 weights [b][sp][k]   : 2 MiB
#define OFF_WH   (2ull << 20)  // u32 half2 W pairs [hp][d]      : 4 MiB
#define OFF_PART (6ull << 20)  // f32 partials [sc][b][k][h]     : 16 MiB
#define OFF_PQ   (22ull << 20) // u32 half2 pooled [b*K+k][hp]   : 1 MiB
#define OFF_PROJ (23ull << 20) // f32 projected [row][d]         : 1 MiB

__device__ __forceinline__ float dot2f(h2 a, h2 b, float c) {
#if defined(__has_builtin)
#if __has_builtin(__builtin_amdgcn_fdot2)
  return __builtin_amdgcn_fdot2(a, b, c, false);
#else
  return fmaf((float)a[0], (float)b[0], fmaf((float)a[1], (float)b[1], c));
#endif
#else
  return fmaf((float)a[0], (float)b[0], fmaf((float)a[1], (float)b[1], c));
#endif
}

__device__ __forceinline__ h2 pk_rtz(float x, float y) {
#if defined(__has_builtin)
#if __has_builtin(__builtin_amdgcn_cvt_pkrtz)
  return __builtin_amdgcn_cvt_pkrtz(x, y);
#else
  h2 r; r[0] = (__fp16)x; r[1] = (__fp16)y; return r;
#endif
#else
  h2 r; r[0] = (__fp16)x; r[1] = (__fp16)y; return r;
#endif
}

__device__ __forceinline__ u32 h2u(h2 v) { union { h2 h; u32 u; } c; c.h = v; return c.u; }
__device__ __forceinline__ h2 u2h(u32 v) { union { h2 h; u32 u; } c; c.u = v; return c.h; }

// ---------------------------------------------------------------------------
// k_weights: per (b,k) block. Detect ownership storage (bytes vs words),
// count owners, write w2[b][sp][k] = half2(own(2sp)*inv, own(2sp+1)*inv).
// ---------------------------------------------------------------------------
__global__ __launch_bounds__(256) void k_weights(const void* __restrict__ own,
                                                 u32* __restrict__ w2) {
  const int bk = blockIdx.x;
  const int b = bk >> 5, k = bk & 31;
  const int t = threadIdx.x;
  __shared__ int s_mode;
  __shared__ int s_wcnt[4];
  __shared__ float s_inv;

  if (t < 64) {
    u32 w = ((const u32*)own)[t];
    bool wordok = (w <= 1u) || (w == 0x3f800000u);
    unsigned long long m = __ballot(wordok);
    if (t == 0) s_mode = (m == ~0ull) ? 1 : 0;  // 1: 4-byte elems, 0: 1-byte bools
  }
  __syncthreads();
  const int mode = s_mode;

  u32 bits = 0;  // bit j = own[b][k][t*16 + j]
  const size_t base = (size_t)bk * SS + (size_t)t * 16;
  if (mode == 0) {
    uint4 v = *(const uint4*)((const unsigned char*)own + base);
    u32 wa[4] = {v.x, v.y, v.z, v.w};
#pragma unroll
    for (int w = 0; w < 4; ++w)
#pragma unroll
      for (int j = 0; j < 4; ++j)
        if ((wa[w] >> (8 * j)) & 0xffu) bits |= 1u << (4 * w + j);
  } else {
    const u32* p = (const u32*)own + base;
#pragma unroll
    for (int j = 0; j < 16; ++j)
      if (p[j] != 0u) bits |= 1u << j;
  }

  int cnt = __popc(bits);
#pragma unroll
  for (int off = 1; off < 64; off <<= 1) cnt += __shfl_xor(cnt, off);
  if ((t & 63) == 0) s_wcnt[t >> 6] = cnt;
  __syncthreads();
  if (t == 0) {
    int tot = s_wcnt[0] + s_wcnt[1] + s_wcnt[2] + s_wcnt[3];
    s_inv = 1.0f / fmaxf((float)tot, 1.0f);
  }
  __syncthreads();
  const float inv = s_inv;

  u32* wo = w2 + ((size_t)b * SP + (size_t)t * 8) * KK + k;
#pragma unroll
  for (int j = 0; j < 8; ++j) {
    float lo = ((bits >> (2 * j)) & 1u) ? inv : 0.0f;
    float hi = ((bits >> (2 * j + 1)) & 1u) ? inv : 0.0f;
    h2 hv; hv[0] = (__fp16)lo; hv[1] = (__fp16)hi;
    wo[(size_t)j * KK] = h2u(hv);
  }
}

// ---------------------------------------------------------------------------
// k_wpack: WH[hp*D + d] = half2(W[2hp][d], W[2hp+1][d])  (RNE)
// ---------------------------------------------------------------------------
__global__ __launch_bounds__(256) void k_wpack(const float* __restrict__ W,
                                               u32* __restrict__ WH) {
  const int i = blockIdx.x * 256 + threadIdx.x;  // grid sized exactly HP*D/256
  const int hp = i >> 10, d = i & (DD - 1);
  float lo = W[(size_t)(2 * hp) * DD + d];
  float hi = W[(size_t)(2 * hp + 1) * DD + d];
  h2 hv; hv[0] = (__fp16)lo; hv[1] = (__fp16)hi;
  WH[i] = h2u(hv);
}

// ---------------------------------------------------------------------------
// k_pool: the 268 MB streamer. Block = (h-chunk 256, b, s-chunk 512).
// Thread <-> one h column, 32 f32 accumulators (one per k), dot2 on f16
// (plan pair, weight pair). 8-deep register prefetch skew hides HBM latency.
// ---------------------------------------------------------------------------
__global__ __launch_bounds__(256) void k_pool(const float* __restrict__ plan,
                                              const u32* __restrict__ w2,
                                              float* __restrict__ part) {
  const int hc = blockIdx.x, b = blockIdx.y, sc = blockIdx.z;
  const int t = threadIdx.x;
  const float* pb = plan + (size_t)b * SS * HH + hc * 256 + t;
  const u32* wrow = w2 + ((size_t)b * SP + (size_t)sc * SPC) * KK;
  const int sp0 = sc * SPC;

  float acc[KK];
#pragma unroll
  for (int k = 0; k < KK; ++k) acc[k] = 0.0f;

  float vx[8], vy[8];
#pragma unroll
  for (int j = 0; j < 8; ++j) {
    vx[j] = pb[(size_t)(2 * (sp0 + j)) * HH];
    vy[j] = pb[(size_t)(2 * (sp0 + j) + 1) * HH];
  }

  for (int i0 = 0; i0 < SPC; i0 += 8) {
#pragma unroll
    for (int j = 0; j < 8; ++j) {
      const int i = i0 + j;
      const float x = vx[j], y = vy[j];
      int nx = i + 8; nx = (nx < SPC) ? nx : (SPC - 1);
      vx[j] = pb[(size_t)(2 * (sp0 + nx)) * HH];
      vy[j] = pb[(size_t)(2 * (sp0 + nx) + 1) * HH];
      const h2 hv = pk_rtz(x, y);
      const u32* wr = wrow + (size_t)i * KK;  // wave-uniform -> s_load expected
#pragma unroll
      for (int k = 0; k < KK; ++k)
        acc[k] = dot2f(hv, u2h(wr[k]), acc[k]);
    }
  }

  float* po = part + ((size_t)sc * BB + b) * KK * HH + hc * 256 + t;
#pragma unroll
  for (int k = 0; k < KK; ++k) po[(size_t)k * HH] = acc[k];
}

// ---------------------------------------------------------------------------
// k_reduce: fold NSC partials, pack pooled as half2 pairs over h.
// ---------------------------------------------------------------------------
__global__ __launch_bounds__(256) void k_reduce(const float* __restrict__ part,
                                                u32* __restrict__ pq) {
  const int i = blockIdx.x * 256 + threadIdx.x;  // over BB*KK*HP = 262144
  const int bk = i >> 10, hp = i & (HP - 1);
  float lo = 0.f, hi = 0.f;
#pragma unroll
  for (int sc = 0; sc < NSC; ++sc) {
    const float* p = part + ((size_t)sc * BB * KK + bk) * HH + 2 * hp;
    lo += p[0];
    hi += p[1];
  }
  h2 hv; hv[0] = (__fp16)lo; hv[1] = (__fp16)hi;
  pq[i] = h2u(hv);
}

// ---------------------------------------------------------------------------
// k_proj: proj[row][c] = sum_h pooled[row][h] * W[h][c] + bias[c]
// Block: 8 rows x 128 cols, hp split in halves across tid>>7; LDS combine.
// ---------------------------------------------------------------------------
__global__ __launch_bounds__(256) void k_proj(const u32* __restrict__ WH,
                                              const u32* __restrict__ pq,
                                              const float* __restrict__ bias,
                                              float* __restrict__ proj) {
  const int rowg = blockIdx.x, colg = blockIdx.y;
  const int t = threadIdx.x;
  const int col = t & 127, hh = t >> 7;
  const int c = colg * 128 + col;
  const u32* wcol = WH + (size_t)(hh * 512) * DD + c;
  const u32* prow = pq + (size_t)rowg * 8 * HP + hh * 512;  // row stride HP

  float acc[8];
#pragma unroll
  for (int r = 0; r < 8; ++r) acc[r] = 0.f;

  u32 wpf[8];
#pragma unroll
  for (int j = 0; j < 8; ++j) wpf[j] = wcol[(size_t)j * DD];

  for (int i0 = 0; i0 < 512; i0 += 8) {
#pragma unroll
    for (int j = 0; j < 8; ++j) {
      const int hp = i0 + j;
      const u32 wvu = wpf[j];
      int nx = hp + 8; nx = (nx < 512) ? nx : 511;
      wpf[j] = wcol[(size_t)nx * DD];
      const h2 wv = u2h(wvu);
#pragma unroll
      for (int r = 0; r < 8; ++r)
        acc[r] = dot2f(u2h(prow[(size_t)r * HP + hp]), wv, acc[r]);
    }
  }

  __shared__ float red[8][128];
  if (hh == 1) {
#pragma unroll
    for (int r = 0; r < 8; ++r) red[r][col] = acc[r];
  }
  __syncthreads();
  if (hh == 0) {
#pragma unroll
    for (int r = 0; r < 8; ++r) {
      float v = acc[r] + red[r][col] + bias[c];
      proj[(size_t)(rowg * 8 + r) * DD + c] = v;
    }
  }
}

// ---------------------------------------------------------------------------
// k_ln: LayerNorm over D=1024, one block per row.
// ---------------------------------------------------------------------------
__global__ __launch_bounds__(256) void k_ln(const float* __restrict__ proj,
                                            const float* __restrict__ gamma,
                                            const float* __restrict__ beta,
                                            float* __restrict__ out) {
  const int row = blockIdx.x, t = threadIdx.x;
  float4 v = ((const float4*)(proj + (size_t)row * DD))[t];
  float s1 = v.x + v.y + v.z + v.w;
  float s2 = v.x * v.x + v.y * v.y + v.z * v.z + v.w * v.w;
#pragma unroll
  for (int off = 1; off < 64; off <<= 1) {
    s1 += __shfl_xor(s1, off);
    s2 += __shfl_xor(s2, off);
  }
  __shared__ float a1[4], a2[4];
  if ((t & 63) == 0) { a1[t >> 6] = s1; a2[t >> 6] = s2; }
  __syncthreads();
  const float S1 = a1[0] + a1[1] + a1[2] + a1[3];
  const float S2 = a2[0] + a2[1] + a2[2] + a2[3];
  const float mu = S1 * (1.0f / DD);
  const float var = S2 * (1.0f / DD) - mu * mu;
  const float rs = rsqrtf(var + 1e-5f);
  float4 g = ((const float4*)gamma)[t];
  float4 be = ((const float4*)beta)[t];
  float4 o;
  o.x = (v.x - mu) * rs * g.x + be.x;
  o.y = (v.y - mu) * rs * g.y + be.y;
  o.z = (v.z - mu) * rs * g.z + be.z;
  o.w = (v.w - mu) * rs * g.w + be.w;
  ((float4*)(out + (size_t)row * DD))[t] = o;
}

// ---------------------------------------------------------------------------

extern "C" void kernel_launch(void* const* d_in, const int* in_sizes, int n_in,
                              void* d_out, int out_size, void* d_ws, size_t ws_size,
                              hipStream_t stream) {
  (void)in_sizes; (void)n_in; (void)out_size; (void)ws_size;
  const float* plan  = (const float*)d_in[0];
  const void*  own   = d_in[1];
  const float* W     = (const float*)d_in[2];
  const float* bias  = (const float*)d_in[3];
  const float* gamma = (const float*)d_in[4];
  const float* beta  = (const float*)d_in[5];
  float* out = (float*)d_out;
  char* ws = (char*)d_ws;

  u32*   w2   = (u32*)(ws + OFF_W2);
  u32*   WH   = (u32*)(ws + OFF_WH);
  float* part = (float*)(ws + OFF_PART);
  u32*   pq   = (u32*)(ws + OFF_PQ);
  float* proj = (float*)(ws + OFF_PROJ);

  k_weights<<<dim3(BB * KK), dim3(256), 0, stream>>>(own, w2);
  k_wpack<<<dim3((HP * DD) / 256), dim3(256), 0, stream>>>(W, WH);
  k_pool<<<dim3(HH / 256, BB, NSC), dim3(256), 0, stream>>>(plan, w2, part);
  k_reduce<<<dim3((BB * KK * HP) / 256), dim3(256), 0, stream>>>(part, pq);
  k_proj<<<dim3(BB * KK / 8, DD / 128), dim3(256), 0, stream>>>(WH, pq, bias, proj);
  k_ln<<<dim3(BB * KK), dim3(256), 0, stream>>>(proj, gamma, beta, out);
}

// Round 4
// 100.152 us; speedup vs baseline: 1.8207x; 1.8207x over previous
//
#include <hip/hip_runtime.h>

typedef unsigned int u32;
typedef unsigned short u16;
typedef __attribute__((ext_vector_type(8))) short short8;
typedef __attribute__((ext_vector_type(4))) float f32x4;

#define BB 8
#define KK 32
#define SS 4096
#define HH 2048
#define DD 1024
#define NSC 8        // s-chunks in pooling
#define SC_S 512     // s per chunk
#define NSLAB 16     // SC_S / 32

// ws layout (bytes); total 24 MiB
#define OFF_W16  0ull           // bf16 [b][k][s]        : 2 MiB
#define OFF_WB   (2ull << 20)   // bf16 [d][h] (W^T)     : 4 MiB
#define OFF_PART (6ull << 20)   // f32 [sc][b][k][h]     : 16 MiB
#define OFF_PQ   (22ull << 20)  // bf16 [row][h] pooled  : 1 MiB
#define OFF_PROJ (23ull << 20)  // f32 [row][d]          : 1 MiB

__device__ __forceinline__ u16 f2bf(float x) {
  u32 u = __float_as_uint(x);
  return (u16)((u + 0x7fffu + ((u >> 16) & 1u)) >> 16);  // RNE
}

// ---------------------------------------------------------------------------
// k_weights: per (b,k) block. Detect ownership storage (1-byte bool vs 4-byte
// word), count owners, write bf16 weights w16[b][k][s] = own ? 1/cnt : 0.
// Output is s-major so pooling A-fragments are 16B contiguous lane loads.
// ---------------------------------------------------------------------------
__global__ __launch_bounds__(256) void k_weights(const void* __restrict__ own,
                                                 u16* __restrict__ w16) {
  const int bk = blockIdx.x;          // bk = b*32 + k
  const int t = threadIdx.x;
  __shared__ int s_mode;
  __shared__ int s_wcnt[4];
  __shared__ float s_inv;

  if (t < 64) {
    u32 w = ((const u32*)own)[t];
    bool wordok = (w <= 1u) || (w == 0x3f800000u);
    unsigned long long m = __ballot(wordok);
    if (t == 0) s_mode = (m == ~0ull) ? 1 : 0;  // 1: 4-byte elems, 0: bytes
  }
  __syncthreads();
  const int mode = s_mode;

  u32 bits = 0;  // bit j = own[b][k][t*16 + j]
  const size_t base = (size_t)bk * SS + (size_t)t * 16;
  if (mode == 0) {
    uint4 v = *(const uint4*)((const unsigned char*)own + base);
    u32 wa[4] = {v.x, v.y, v.z, v.w};
#pragma unroll
    for (int w = 0; w < 4; ++w)
#pragma unroll
      for (int j = 0; j < 4; ++j)
        if ((wa[w] >> (8 * j)) & 0xffu) bits |= 1u << (4 * w + j);
  } else {
    const u32* p = (const u32*)own + base;
#pragma unroll
    for (int j = 0; j < 16; ++j)
      if (p[j] != 0u) bits |= 1u << j;
  }

  int cnt = __popc(bits);
#pragma unroll
  for (int off = 1; off < 64; off <<= 1) cnt += __shfl_xor(cnt, off);
  if ((t & 63) == 0) s_wcnt[t >> 6] = cnt;
  __syncthreads();
  if (t == 0) {
    int tot = s_wcnt[0] + s_wcnt[1] + s_wcnt[2] + s_wcnt[3];
    s_inv = 1.0f / fmaxf((float)tot, 1.0f);
  }
  __syncthreads();
  const u32 hv = (u32)f2bf(s_inv);

  u32 outw[8];
#pragma unroll
  for (int j = 0; j < 8; ++j) {
    u32 lo = ((bits >> (2 * j)) & 1u) ? hv : 0u;
    u32 hi = ((bits >> (2 * j + 1)) & 1u) ? hv : 0u;
    outw[j] = lo | (hi << 16);
  }
  u32* wo = (u32*)w16 + (size_t)bk * (SS / 2) + (size_t)t * 8;
  uint4 o0 = {outw[0], outw[1], outw[2], outw[3]};
  uint4 o1 = {outw[4], outw[5], outw[6], outw[7]};
  ((uint4*)wo)[0] = o0;
  ((uint4*)wo)[1] = o1;
}

// ---------------------------------------------------------------------------
// k_wpackT: WB[d][h] = bf16(W[h][d]) via LDS tile transpose (64x64, pad 65).
// ---------------------------------------------------------------------------
__global__ __launch_bounds__(256) void k_wpackT(const float* __restrict__ W,
                                                u16* __restrict__ WB) {
  __shared__ float lds[64][65];
  const int hb = blockIdx.x * 64, db = blockIdx.y * 64;
  const int x = threadIdx.x & 63, y = threadIdx.x >> 6;
#pragma unroll
  for (int j = 0; j < 16; ++j) {
    int r = y + 4 * j;
    lds[r][x] = W[(size_t)(hb + r) * DD + db + x];
  }
  __syncthreads();
#pragma unroll
  for (int j = 0; j < 16; ++j) {
    int r = y + 4 * j;
    WB[(size_t)(db + r) * HH + hb + x] = f2bf(lds[x][r]);
  }
}

// ---------------------------------------------------------------------------
// k_pool: MFMA pooling. Per batch: part[k][h] += W16[32 x 512sc] * plan[512 x h].
// Wave handles 32 h-cols x all 32 k-rows over one 512-s chunk.
// A-frags (weights) from registers, B-frags streamed from plan (f32->bf16).
// No wave-uniform loads anywhere in the hot loop.
// ---------------------------------------------------------------------------
__global__ __launch_bounds__(256) void k_pool(const float* __restrict__ plan,
                                              const u16* __restrict__ w16,
                                              float* __restrict__ part) {
  const int hcl = blockIdx.x, sc = blockIdx.y, b = blockIdx.z;
  const int t = threadIdx.x, w = t >> 6, l = t & 63;
  const int lr = l & 15, lg = l >> 4;  // row/col-in-tile, k-octet group
  const int h0 = hcl * 128 + w * 32;
  const int s0 = sc * SC_S;

  const float* pb = plan + (size_t)b * SS * HH;
  f32x4 acc[2][2];  // [h-tile][k-tile]
#pragma unroll
  for (int a = 0; a < 2; ++a)
#pragma unroll
    for (int c = 0; c < 2; ++c) acc[a][c] = (f32x4){0.f, 0.f, 0.f, 0.f};

  for (int slab = 0; slab < NSLAB; ++slab) {
    const int sbase = s0 + slab * 32 + lg * 8;
    // A-fragments: lane lr = k-row, 8 contiguous s at lg*8
    short8 a0 = *(const short8*)(w16 + ((size_t)(b * KK + lr) * SS + sbase));
    short8 a1 = *(const short8*)(w16 + ((size_t)(b * KK + 16 + lr) * SS + sbase));
#pragma unroll
    for (int tt = 0; tt < 2; ++tt) {
      const float* col = pb + (size_t)sbase * HH + h0 + tt * 16 + lr;
      float f[8];
#pragma unroll
      for (int j = 0; j < 8; ++j) f[j] = col[(size_t)j * HH];
      short8 bfr;
#pragma unroll
      for (int j = 0; j < 8; ++j) bfr[j] = (short)f2bf(f[j]);
      acc[tt][0] = __builtin_amdgcn_mfma_f32_16x16x32_bf16(a0, bfr, acc[tt][0], 0, 0, 0);
      acc[tt][1] = __builtin_amdgcn_mfma_f32_16x16x32_bf16(a1, bfr, acc[tt][1], 0, 0, 0);
    }
  }

  // C layout: col = lane&15, row = (lane>>4)*4 + reg
  float* po = part + ((size_t)sc * BB + b) * KK * HH;
#pragma unroll
  for (int tt = 0; tt < 2; ++tt)
#pragma unroll
    for (int kt = 0; kt < 2; ++kt)
#pragma unroll
      for (int j = 0; j < 4; ++j) {
        int krow = kt * 16 + lg * 4 + j;
        int hcol = h0 + tt * 16 + lr;
        po[(size_t)krow * HH + hcol] = acc[tt][kt][j];
      }
}

// ---------------------------------------------------------------------------
// k_reduce: fold 8 s-chunk partials, pack pooled rows to bf16 (h-major).
// ---------------------------------------------------------------------------
__global__ __launch_bounds__(256) void k_reduce(const float* __restrict__ part,
                                                u32* __restrict__ pq) {
  const int i = blockIdx.x * 256 + threadIdx.x;  // over 256 rows * 1024 h-pairs
  const int row = i >> 10, hp = i & 1023;
  const float* p = part + (size_t)row * HH + 2 * hp;
  float lo = 0.f, hi = 0.f;
#pragma unroll
  for (int sc = 0; sc < NSC; ++sc) {
    float2 v = *(const float2*)(p + (size_t)sc * BB * KK * HH);
    lo += v.x;
    hi += v.y;
  }
  pq[i] = (u32)f2bf(lo) | ((u32)f2bf(hi) << 16);
}

// ---------------------------------------------------------------------------
// k_proj: MFMA projection. proj[256 x 1024] = pooled[256 x 2048] @ W + bias.
// Both operands L2-resident bf16, 16B contiguous lane loads.
// ---------------------------------------------------------------------------
__global__ __launch_bounds__(256) void k_proj(const u16* __restrict__ pq,
                                              const u16* __restrict__ WB,
                                              const float* __restrict__ bias,
                                              float* __restrict__ proj) {
  const int rt = blockIdx.x, ctg = blockIdx.y;
  const int t = threadIdx.x, w = t >> 6, l = t & 63;
  const int lr = l & 15, lg = l >> 4;
  const int r0 = rt * 16, c0 = (ctg * 4 + w) * 16;

  const u16* pa = pq + (size_t)(r0 + lr) * HH + lg * 8;
  const u16* pw = WB + (size_t)(c0 + lr) * HH + lg * 8;
  f32x4 acc = (f32x4){0.f, 0.f, 0.f, 0.f};
#pragma unroll 4
  for (int slab = 0; slab < 64; ++slab) {
    short8 a = *(const short8*)(pa + slab * 32);
    short8 bv = *(const short8*)(pw + slab * 32);
    acc = __builtin_amdgcn_mfma_f32_16x16x32_bf16(a, bv, acc, 0, 0, 0);
  }
  const float bs = bias[c0 + lr];
#pragma unroll
  for (int j = 0; j < 4; ++j)
    proj[(size_t)(r0 + lg * 4 + j) * DD + c0 + lr] = acc[j] + bs;
}

// ---------------------------------------------------------------------------
// k_ln: LayerNorm over D=1024, one block per row (exact ref math, f32).
// ---------------------------------------------------------------------------
__global__ __launch_bounds__(256) void k_ln(const float* __restrict__ proj,
                                            const float* __restrict__ gamma,
                                            const float* __restrict__ beta,
                                            float* __restrict__ out) {
  const int row = blockIdx.x, t = threadIdx.x;
  float4 v = ((const float4*)(proj + (size_t)row * DD))[t];
  float s1 = v.x + v.y + v.z + v.w;
  float s2 = v.x * v.x + v.y * v.y + v.z * v.z + v.w * v.w;
#pragma unroll
  for (int off = 1; off < 64; off <<= 1) {
    s1 += __shfl_xor(s1, off);
    s2 += __shfl_xor(s2, off);
  }
  __shared__ float a1[4], a2[4];
  if ((t & 63) == 0) { a1[t >> 6] = s1; a2[t >> 6] = s2; }
  __syncthreads();
  const float S1 = a1[0] + a1[1] + a1[2] + a1[3];
  const float S2 = a2[0] + a2[1] + a2[2] + a2[3];
  const float mu = S1 * (1.0f / DD);
  const float var = S2 * (1.0f / DD) - mu * mu;
  const float rs = rsqrtf(var + 1e-5f);
  float4 g = ((const float4*)gamma)[t];
  float4 be = ((const float4*)beta)[t];
  float4 o;
  o.x = (v.x - mu) * rs * g.x + be.x;
  o.y = (v.y - mu) * rs * g.y + be.y;
  o.z = (v.z - mu) * rs * g.z + be.z;
  o.w = (v.w - mu) * rs * g.w + be.w;
  ((float4*)(out + (size_t)row * DD))[t] = o;
}

// ---------------------------------------------------------------------------

extern "C" void kernel_launch(void* const* d_in, const int* in_sizes, int n_in,
                              void* d_out, int out_size, void* d_ws, size_t ws_size,
                              hipStream_t stream) {
  (void)in_sizes; (void)n_in; (void)out_size; (void)ws_size;
  const float* plan  = (const float*)d_in[0];
  const void*  own   = d_in[1];
  const float* W     = (const float*)d_in[2];
  const float* bias  = (const float*)d_in[3];
  const float* gamma = (const float*)d_in[4];
  const float* beta  = (const float*)d_in[5];
  float* out = (float*)d_out;
  char* ws = (char*)d_ws;

  u16*   w16  = (u16*)(ws + OFF_W16);
  u16*   WB   = (u16*)(ws + OFF_WB);
  float* part = (float*)(ws + OFF_PART);
  u32*   pq   = (u32*)(ws + OFF_PQ);
  float* proj = (float*)(ws + OFF_PROJ);

  k_weights<<<dim3(BB * KK), dim3(256), 0, stream>>>(own, w16);
  k_wpackT<<<dim3(HH / 64, DD / 64), dim3(256), 0, stream>>>(W, WB);
  k_pool<<<dim3(16, NSC, BB), dim3(256), 0, stream>>>(plan, w16, part);
  k_reduce<<<dim3((BB * KK * (HH / 2)) / 256), dim3(256), 0, stream>>>(part, pq);
  k_proj<<<dim3(16, 16), dim3(256), 0, stream>>>((const u16*)pq, WB, bias, proj);
  k_ln<<<dim3(BB * KK), dim3(256), 0, stream>>>(proj, gamma, beta, out);
}

// Round 5
// 87.885 us; speedup vs baseline: 2.0748x; 1.1396x over previous
//
#include <hip/hip_runtime.h>

typedef unsigned int u32;
typedef unsigned short u16;
typedef __attribute__((ext_vector_type(8))) short short8;
typedef __attribute__((ext_vector_type(4))) float f32x4;
typedef __attribute__((ext_vector_type(16))) float f32x16;

#define BB 8
#define KK 32
#define SS 4096
#define HH 2048
#define DD 1024
#define NSC 8        // s-chunks in pooling
#define SC_S 512     // s per chunk
#define KSTEPS 32    // SC_S / 16

// ws layout (bytes); total 24 MiB (ws is ~1 GiB per harness fills)
#define OFF_W16  0ull           // bf16 [b][k][s]        : 2 MiB
#define OFF_WB   (2ull << 20)   // bf16 [d][h] (W^T)     : 4 MiB
#define OFF_PART (6ull << 20)   // f32 [sc][b][k][h]     : 16 MiB
#define OFF_PQ   (22ull << 20)  // bf16 [row][h] pooled  : 1 MiB
#define OFF_PROJ (23ull << 20)  // f32 [row][d]          : 1 MiB

__device__ __forceinline__ u16 f2bf(float x) {
  u32 u = __float_as_uint(x);
  return (u16)((u + 0x7fffu + ((u >> 16) & 1u)) >> 16);  // RNE
}

// ---------------------------------------------------------------------------
// k_prep: dual-role. Blocks [0, 256): ownership -> bf16 weights w16[b][k][s].
// Blocks [256, 768): W[h][d] -> WB[d][h] bf16 via LDS 64x64 transpose.
// ---------------------------------------------------------------------------
__global__ __launch_bounds__(256) void k_prep(const void* __restrict__ own,
                                              u16* __restrict__ w16,
                                              const float* __restrict__ W,
                                              u16* __restrict__ WB) {
  __shared__ float lds[64][65];  // wpackT role; weights role reuses a corner
  const int t = threadIdx.x;

  if (blockIdx.x < BB * KK) {
    // ---- weights role ----
    const int bk = blockIdx.x;  // b*32 + k
    __shared__ int s_mode;
    __shared__ int s_wcnt[4];
    __shared__ float s_inv;

    if (t < 64) {
      u32 w = ((const u32*)own)[t];
      bool wordok = (w <= 1u) || (w == 0x3f800000u);
      unsigned long long m = __ballot(wordok);
      if (t == 0) s_mode = (m == ~0ull) ? 1 : 0;  // 1: 4-byte elems, 0: bytes
    }
    __syncthreads();
    const int mode = s_mode;

    u32 bits = 0;  // bit j = own[b][k][t*16 + j]
    const size_t base = (size_t)bk * SS + (size_t)t * 16;
    if (mode == 0) {
      uint4 v = *(const uint4*)((const unsigned char*)own + base);
      u32 wa[4] = {v.x, v.y, v.z, v.w};
#pragma unroll
      for (int w = 0; w < 4; ++w)
#pragma unroll
        for (int j = 0; j < 4; ++j)
          if ((wa[w] >> (8 * j)) & 0xffu) bits |= 1u << (4 * w + j);
    } else {
      const u32* p = (const u32*)own + base;
#pragma unroll
      for (int j = 0; j < 16; ++j)
        if (p[j] != 0u) bits |= 1u << j;
    }

    int cnt = __popc(bits);
#pragma unroll
    for (int off = 1; off < 64; off <<= 1) cnt += __shfl_xor(cnt, off);
    if ((t & 63) == 0) s_wcnt[t >> 6] = cnt;
    __syncthreads();
    if (t == 0) {
      int tot = s_wcnt[0] + s_wcnt[1] + s_wcnt[2] + s_wcnt[3];
      s_inv = 1.0f / fmaxf((float)tot, 1.0f);
    }
    __syncthreads();
    const u32 hv = (u32)f2bf(s_inv);

    u32 outw[8];
#pragma unroll
    for (int j = 0; j < 8; ++j) {
      u32 lo = ((bits >> (2 * j)) & 1u) ? hv : 0u;
      u32 hi = ((bits >> (2 * j + 1)) & 1u) ? hv : 0u;
      outw[j] = lo | (hi << 16);
    }
    u32* wo = (u32*)w16 + (size_t)bk * (SS / 2) + (size_t)t * 8;
    uint4 o0 = {outw[0], outw[1], outw[2], outw[3]};
    uint4 o1 = {outw[4], outw[5], outw[6], outw[7]};
    ((uint4*)wo)[0] = o0;
    ((uint4*)wo)[1] = o1;
  } else {
    // ---- W-transpose role ----
    const int bidx = blockIdx.x - BB * KK;   // 0..511
    const int hb = (bidx & 31) * 64, db = (bidx >> 5) * 64;
    const int x = t & 63, y = t >> 6;
#pragma unroll
    for (int j = 0; j < 16; ++j) {
      int r = y + 4 * j;
      lds[r][x] = W[(size_t)(hb + r) * DD + db + x];
    }
    __syncthreads();
#pragma unroll
    for (int j = 0; j < 16; ++j) {
      int r = y + 4 * j;
      WB[(size_t)(db + r) * HH + hb + x] = f2bf(lds[x][r]);
    }
  }
}

// ---------------------------------------------------------------------------
// k_pool: MFMA pooling with 32x32x16 tiles. Per wave: one 32-h tile, all 32 k.
// B-load coalescing: per dword instr = 2 contiguous 128B segments.
// A (weights) from registers, 16B contiguous per lane. No uniform loads.
// ---------------------------------------------------------------------------
__global__ __launch_bounds__(256) void k_pool(const float* __restrict__ plan,
                                              const u16* __restrict__ w16,
                                              float* __restrict__ part) {
  const int hcl = blockIdx.x, sc = blockIdx.y, b = blockIdx.z;
  const int t = threadIdx.x, w = t >> 6, l = t & 63;
  const int lc = l & 31, half = l >> 5;
  const int h0 = hcl * 128 + w * 32;
  const int s0 = sc * SC_S;

  const float* pb = plan + (size_t)b * SS * HH + h0 + lc;
  const u16* wa = w16 + (size_t)(b * KK + lc) * SS;

  f32x16 acc;
#pragma unroll
  for (int r = 0; r < 16; ++r) acc[r] = 0.0f;

  for (int step = 0; step < KSTEPS; ++step) {
    const int sb = s0 + step * 16 + half * 8;
    // A: lane lc = k-row, 8 contiguous s at k-slot half*8
    short8 a = *(const short8*)(wa + sb);
    // B: lane lc = h-col, 8 s rows (stride HH)
    const float* col = pb + (size_t)sb * HH;
    float f[8];
#pragma unroll
    for (int j = 0; j < 8; ++j) f[j] = col[(size_t)j * HH];
    short8 bfr;
#pragma unroll
    for (int j = 0; j < 8; ++j) bfr[j] = (short)f2bf(f[j]);
    acc = __builtin_amdgcn_mfma_f32_32x32x16_bf16(a, bfr, acc, 0, 0, 0);
  }

  // C layout: col = lane&31, row = (reg&3) + 8*(reg>>2) + 4*(lane>>5)
  float* po = part + ((size_t)sc * BB + b) * KK * HH + h0 + lc;
#pragma unroll
  for (int r = 0; r < 16; ++r) {
    int krow = (r & 3) + 8 * (r >> 2) + 4 * half;
    po[(size_t)krow * HH] = acc[r];
  }
}

// ---------------------------------------------------------------------------
// k_reduce: fold 8 s-chunk partials, pack pooled rows to bf16 (h-major).
// ---------------------------------------------------------------------------
__global__ __launch_bounds__(256) void k_reduce(const float* __restrict__ part,
                                                u32* __restrict__ pq) {
  const int i = blockIdx.x * 256 + threadIdx.x;  // over 256 rows * 1024 h-pairs
  const int row = i >> 10, hp = i & 1023;
  const float* p = part + (size_t)row * HH + 2 * hp;
  float lo = 0.f, hi = 0.f;
#pragma unroll
  for (int sc = 0; sc < NSC; ++sc) {
    float2 v = *(const float2*)(p + (size_t)sc * BB * KK * HH);
    lo += v.x;
    hi += v.y;
  }
  pq[i] = (u32)f2bf(lo) | ((u32)f2bf(hi) << 16);
}

// ---------------------------------------------------------------------------
// k_proj: MFMA projection. proj[256 x 1024] = pooled[256 x 2048] @ W + bias.
// Both operands L2-resident bf16, 16B contiguous lane loads.
// ---------------------------------------------------------------------------
__global__ __launch_bounds__(256) void k_proj(const u16* __restrict__ pq,
                                              const u16* __restrict__ WB,
                                              const float* __restrict__ bias,
                                              float* __restrict__ proj) {
  const int rt = blockIdx.x, ctg = blockIdx.y;
  const int t = threadIdx.x, w = t >> 6, l = t & 63;
  const int lr = l & 15, lg = l >> 4;
  const int r0 = rt * 16, c0 = (ctg * 4 + w) * 16;

  const u16* pa = pq + (size_t)(r0 + lr) * HH + lg * 8;
  const u16* pw = WB + (size_t)(c0 + lr) * HH + lg * 8;
  f32x4 acc = (f32x4){0.f, 0.f, 0.f, 0.f};
#pragma unroll 4
  for (int slab = 0; slab < 64; ++slab) {
    short8 a = *(const short8*)(pa + slab * 32);
    short8 bv = *(const short8*)(pw + slab * 32);
    acc = __builtin_amdgcn_mfma_f32_16x16x32_bf16(a, bv, acc, 0, 0, 0);
  }
  const float bs = bias[c0 + lr];
#pragma unroll
  for (int j = 0; j < 4; ++j)
    proj[(size_t)(r0 + lg * 4 + j) * DD + c0 + lr] = acc[j] + bs;
}

// ---------------------------------------------------------------------------
// k_ln: LayerNorm over D=1024, one block per row (exact ref math, f32).
// ---------------------------------------------------------------------------
__global__ __launch_bounds__(256) void k_ln(const float* __restrict__ proj,
                                            const float* __restrict__ gamma,
                                            const float* __restrict__ beta,
                                            float* __restrict__ out) {
  const int row = blockIdx.x, t = threadIdx.x;
  float4 v = ((const float4*)(proj + (size_t)row * DD))[t];
  float s1 = v.x + v.y + v.z + v.w;
  float s2 = v.x * v.x + v.y * v.y + v.z * v.z + v.w * v.w;
#pragma unroll
  for (int off = 1; off < 64; off <<= 1) {
    s1 += __shfl_xor(s1, off);
    s2 += __shfl_xor(s2, off);
  }
  __shared__ float a1[4], a2[4];
  if ((t & 63) == 0) { a1[t >> 6] = s1; a2[t >> 6] = s2; }
  __syncthreads();
  const float S1 = a1[0] + a1[1] + a1[2] + a1[3];
  const float S2 = a2[0] + a2[1] + a2[2] + a2[3];
  const float mu = S1 * (1.0f / DD);
  const float var = S2 * (1.0f / DD) - mu * mu;
  const float rs = rsqrtf(var + 1e-5f);
  float4 g = ((const float4*)gamma)[t];
  float4 be = ((const float4*)beta)[t];
  float4 o;
  o.x = (v.x - mu) * rs * g.x + be.x;
  o.y = (v.y - mu) * rs * g.y + be.y;
  o.z = (v.z - mu) * rs * g.z + be.z;
  o.w = (v.w - mu) * rs * g.w + be.w;
  ((float4*)(out + (size_t)row * DD))[t] = o;
}

// ---------------------------------------------------------------------------

extern "C" void kernel_launch(void* const* d_in, const int* in_sizes, int n_in,
                              void* d_out, int out_size, void* d_ws, size_t ws_size,
                              hipStream_t stream) {
  (void)in_sizes; (void)n_in; (void)out_size; (void)ws_size;
  const float* plan  = (const float*)d_in[0];
  const void*  own   = d_in[1];
  const float* W     = (const float*)d_in[2];
  const float* bias  = (const float*)d_in[3];
  const float* gamma = (const float*)d_in[4];
  const float* beta  = (const float*)d_in[5];
  float* out = (float*)d_out;
  char* ws = (char*)d_ws;

  u16*   w16  = (u16*)(ws + OFF_W16);
  u16*   WB   = (u16*)(ws + OFF_WB);
  float* part = (float*)(ws + OFF_PART);
  u32*   pq   = (u32*)(ws + OFF_PQ);
  float* proj = (float*)(ws + OFF_PROJ);

  k_prep<<<dim3(BB * KK + (HH / 64) * (DD / 64)), dim3(256), 0, stream>>>(own, w16, W, WB);
  k_pool<<<dim3(16, NSC, BB), dim3(256), 0, stream>>>(plan, w16, part);
  k_reduce<<<dim3((BB * KK * (HH / 2)) / 256), dim3(256), 0, stream>>>(part, pq);
  k_proj<<<dim3(16, 16), dim3(256), 0, stream>>>((const u16*)pq, WB, bias, proj);
  k_ln<<<dim3(BB * KK), dim3(256), 0, stream>>>(proj, gamma, beta, out);
}